// Round 2
// baseline (217.841 us; speedup 1.0000x reference)
//
#include <hip/hip_runtime.h>
#include <stdint.h>

// Problem constants: B=32, S=10, D=4096, K=8192
#define B_ 32
#define S_ 10
#define D_ 4096
#define K_ 8192
#define RPB 21                 // rows per batch in A: 10 pq + 10 pp + 1 qq
#define M_REAL (B_ * RPB)      // 672

// ---------------- MFMA path geometry ----------------
#define BM 128
#define BN 128
#define BK 32
#define M_PAD_MF 768           // 6 tiles of 128
#define KSPLIT 2
#define KHALF (D_ / KSPLIT)    // 2048

typedef __bf16 bf16x8 __attribute__((ext_vector_type(8)));
typedef float f32x4 __attribute__((ext_vector_type(4)));
typedef unsigned short us4 __attribute__((ext_vector_type(4)));

// ---- bf16 split helpers (RNE, no nan/inf in data) ----
__device__ __forceinline__ unsigned short f2bf(float x) {
  union { float f; uint32_t u; } v; v.f = x;
  uint32_t u = v.u + 0x7fffu + ((v.u >> 16) & 1u);
  return (unsigned short)(u >> 16);
}
__device__ __forceinline__ float bf2f(unsigned short h) {
  union { uint32_t u; float f; } v; v.u = ((uint32_t)h) << 16;
  return v.f;
}
__device__ __forceinline__ void split2(float x, unsigned short& hi, unsigned short& lo) {
  hi = f2bf(x);
  lo = f2bf(x - bf2f(hi));
}

__device__ __forceinline__ void async16(const void* g, void* l) {
  __builtin_amdgcn_global_load_lds(
      (const __attribute__((address_space(1))) unsigned int*)g,
      (__attribute__((address_space(3))) unsigned int*)l, 16, 0, 0);
}

// ---------------------------------------------------------------------------
// MFMA prepass 1: W2 = W*W (fp32), split into bf16 hi/lo planes.
// ---------------------------------------------------------------------------
__global__ __launch_bounds__(256)
void split_w(const float* __restrict__ W, unsigned short* __restrict__ Whi,
             unsigned short* __restrict__ Wlo) {
  size_t i4 = (size_t)blockIdx.x * 256 + threadIdx.x;   // over K_*D_/4 float4s
  float4 w = ((const float4*)W)[i4];
  float a = w.x * w.x, b = w.y * w.y, c = w.z * w.z, d = w.w * w.w;
  us4 hi, lo;
  split2(a, ((unsigned short*)&hi)[0], ((unsigned short*)&lo)[0]);
  split2(b, ((unsigned short*)&hi)[1], ((unsigned short*)&lo)[1]);
  split2(c, ((unsigned short*)&hi)[2], ((unsigned short*)&lo)[2]);
  split2(d, ((unsigned short*)&hi)[3], ((unsigned short*)&lo)[3]);
  ((us4*)Whi)[i4] = hi;
  ((us4*)Wlo)[i4] = lo;
}

// ---------------------------------------------------------------------------
// MFMA prepass 2: build A rows (pq / pp / qq) fp32, split into bf16 hi/lo.
// ---------------------------------------------------------------------------
__global__ __launch_bounds__(256)
void build_a_split(const float* __restrict__ p, const float* __restrict__ q,
                   unsigned short* __restrict__ Ahi, unsigned short* __restrict__ Alo) {
  size_t idx = (size_t)blockIdx.x * 256 + threadIdx.x;  // over M_PAD_MF * 1024 float4s
  int d4 = (int)(idx & 1023);
  int m = (int)(idx >> 10);
  float4 v = make_float4(0.f, 0.f, 0.f, 0.f);
  if (m < M_REAL) {
    int b = m / RPB;
    int r = m - b * RPB;
    const float4* q4 = (const float4*)(q + (size_t)(b * S_ + (S_ - 1)) * D_);
    if (r < S_) {
      const float4* p4 = (const float4*)(p + (size_t)(b * S_ + r) * D_);
      float4 pv = p4[d4]; float4 qv = q4[d4];
      v = make_float4(pv.x * qv.x, pv.y * qv.y, pv.z * qv.z, pv.w * qv.w);
    } else if (r < 2 * S_) {
      const float4* p4 = (const float4*)(p + (size_t)(b * S_ + (r - S_)) * D_);
      float4 pv = p4[d4];
      v = make_float4(pv.x * pv.x, pv.y * pv.y, pv.z * pv.z, pv.w * pv.w);
    } else {
      float4 qv = q4[d4];
      v = make_float4(qv.x * qv.x, qv.y * qv.y, qv.z * qv.z, qv.w * qv.w);
    }
  }
  us4 hi, lo;
  split2(v.x, ((unsigned short*)&hi)[0], ((unsigned short*)&lo)[0]);
  split2(v.y, ((unsigned short*)&hi)[1], ((unsigned short*)&lo)[1]);
  split2(v.z, ((unsigned short*)&hi)[2], ((unsigned short*)&lo)[2]);
  split2(v.w, ((unsigned short*)&hi)[3], ((unsigned short*)&lo)[3]);
  ((us4*)Ahi)[idx] = hi;
  ((us4*)Alo)[idx] = lo;
}

// ---------------------------------------------------------------------------
// MFMA GEMM: G[ks][m][k] = sum_{d in half ks} A[m][d] * W2[k][d]
// 3-term split accumulate: AhiWhi + AhiWlo + AloWhi.
// 128x128x32 tile, 4 waves (2x2), wave tile 64x64 (4x4 frags of 16x16).
// global_load_lds (16B) into linear LDS; XOR-swizzled global source so
// ds_read_b128 fragment reads are bank-conflict-minimal (m173/m201 pattern).
// ---------------------------------------------------------------------------
__global__ __launch_bounds__(256)
void gemm_mfma(const unsigned short* __restrict__ Ahi, const unsigned short* __restrict__ Alo,
               const unsigned short* __restrict__ Whi, const unsigned short* __restrict__ Wlo,
               float* __restrict__ G) {
  // 4 tiles of [128][32] bf16 = 8KB each: 0=Ahi 1=Alo 2=Whi 3=Wlo
  __shared__ unsigned short lds[4 * 128 * 32];
  const int tid = threadIdx.x;
  const int lane = tid & 63;
  const int wid = tid >> 6;
  const int m0 = blockIdx.y * BM;
  const int n0 = blockIdx.x * BN;
  const int ks = blockIdx.z;
  const int d_base = ks * KHALF;

  // ---- staging setup: 8 global_load_lds issues per k-step ----
  const unsigned short* gp[8];
  uint32_t ldsoff[8];  // bytes, wave-uniform
  {
    const unsigned short* planes[4] = {Ahi, Alo, Whi, Wlo};
    const int rowg[4] = {m0, m0, n0, n0};
#pragma unroll
    for (int t = 0; t < 4; ++t)
#pragma unroll
      for (int half = 0; half < 2; ++half) {
        int e = t * 2 + half;
        int row = half * 64 + wid * 16 + (lane >> 2);      // row within tile
        int k16p = lane & 3;                               // physical 16B chunk
        int k16l = k16p ^ ((row ^ (row >> 2)) & 3);        // logical chunk (swizzle)
        gp[e] = planes[t] + (size_t)(rowg[t] + row) * D_ + d_base + k16l * 8;
        ldsoff[e] = (uint32_t)(t * 8192 + half * 4096 + wid * 1024);
      }
  }

  f32x4 acc[4][4];
#pragma unroll
  for (int i = 0; i < 4; ++i)
#pragma unroll
    for (int j = 0; j < 4; ++j) acc[i][j] = (f32x4){0.f, 0.f, 0.f, 0.f};

  const int wm = wid >> 1;        // wave row in 2x2 grid
  const int wn = wid & 1;
  const int frow = lane & 15;
  const int k16l = lane >> 4;
  int aoff[4], woff[4];           // element offsets within a tile
#pragma unroll
  for (int f = 0; f < 4; ++f) {
    int ra = wm * 64 + f * 16 + frow;
    aoff[f] = ra * 32 + ((k16l ^ ((ra ^ (ra >> 2)) & 3)) * 8);
    int rw = wn * 64 + f * 16 + frow;
    woff[f] = rw * 32 + ((k16l ^ ((rw ^ (rw >> 2)) & 3)) * 8);
  }
  const unsigned short* ldsAhi = lds;
  const unsigned short* ldsAlo = lds + 4096;
  const unsigned short* ldsWhi = lds + 8192;
  const unsigned short* ldsWlo = lds + 12288;

  for (int d0 = 0; d0 < KHALF; d0 += BK) {
#pragma unroll
    for (int e = 0; e < 8; ++e)
      async16(gp[e] + d0, (char*)lds + ldsoff[e]);
    __syncthreads();              // drains vmcnt: staged data visible

    bf16x8 aH[4], aL[4];
#pragma unroll
    for (int f = 0; f < 4; ++f) {
      aH[f] = *(const bf16x8*)(ldsAhi + aoff[f]);
      aL[f] = *(const bf16x8*)(ldsAlo + aoff[f]);
    }
#pragma unroll
    for (int nf = 0; nf < 4; ++nf) {
      bf16x8 wH = *(const bf16x8*)(ldsWhi + woff[nf]);
      bf16x8 wL = *(const bf16x8*)(ldsWlo + woff[nf]);
#pragma unroll
      for (int mf = 0; mf < 4; ++mf) {
        acc[mf][nf] = __builtin_amdgcn_mfma_f32_16x16x32_bf16(aH[mf], wH, acc[mf][nf], 0, 0, 0);
        acc[mf][nf] = __builtin_amdgcn_mfma_f32_16x16x32_bf16(aH[mf], wL, acc[mf][nf], 0, 0, 0);
        acc[mf][nf] = __builtin_amdgcn_mfma_f32_16x16x32_bf16(aL[mf], wH, acc[mf][nf], 0, 0, 0);
      }
    }
    __syncthreads();              // protect LDS before next iteration's DMA
  }

  // ---- C write: row=(lane>>4)*4+r, col=lane&15 (verified gfx950 C/D layout) ----
  float* Gp = G + (size_t)ks * M_PAD_MF * K_;
  const int crow = m0 + wm * 64;
  const int ccol = n0 + wn * 64;
#pragma unroll
  for (int mf = 0; mf < 4; ++mf)
#pragma unroll
    for (int nf = 0; nf < 4; ++nf)
#pragma unroll
      for (int r = 0; r < 4; ++r) {
        int row = crow + mf * 16 + (lane >> 4) * 4 + r;
        int col = ccol + nf * 16 + (lane & 15);
        Gp[(size_t)row * K_ + col] = acc[mf][nf][r];
      }
}

// ---------------------------------------------------------------------------
// MFMA epilogue: sum K-split planes, normalize, transpose-write.
// out[b][k][s] = -dot / (sqrt(pp)*sqrt(qq)*D)
// ---------------------------------------------------------------------------
__global__ __launch_bounds__(256)
void epilogue2(const float* __restrict__ G, float* __restrict__ out) {
  __shared__ float buf[256 * S_];
  const int tid = threadIdx.x;
  const int b = blockIdx.y;
  const int k0 = blockIdx.x * 256;
  const int k = k0 + tid;
  const float* G0 = G + (size_t)b * RPB * K_ + k;
  const float* G1 = G0 + (size_t)M_PAD_MF * K_;
  float nq = sqrtf(G0[20 * K_] + G1[20 * K_]);
#pragma unroll
  for (int s = 0; s < S_; ++s) {
    float dot = G0[s * K_] + G1[s * K_];
    float pp = G0[(S_ + s) * K_] + G1[(S_ + s) * K_];
    buf[tid * S_ + s] = -dot / (sqrtf(pp) * nq * (float)D_);
  }
  __syncthreads();
  float* ob = out + ((size_t)b * K_ + k0) * S_;
  for (int i = tid; i < 256 * S_; i += 256) ob[i] = buf[i];
}

// ===========================================================================
// ============ fp32 fallback path (used if ws_size is too small) ============
// ===========================================================================
#define FBM 64
#define FBN 128
#define FBK 16
#define M_PAD_F32 704   // 11 tiles of 64

__global__ __launch_bounds__(256)
void build_A(const float* __restrict__ p, const float* __restrict__ q,
             float* __restrict__ A) {
  int idx = blockIdx.x * 256 + threadIdx.x;
  int d4 = idx & 1023;
  int m = idx >> 10;
  float4 v = make_float4(0.f, 0.f, 0.f, 0.f);
  if (m < M_REAL) {
    int b = m / RPB;
    int r = m - b * RPB;
    const float4* q4 = (const float4*)(q + (size_t)(b * S_ + (S_ - 1)) * D_);
    if (r < S_) {
      const float4* p4 = (const float4*)(p + (size_t)(b * S_ + r) * D_);
      float4 pv = p4[d4]; float4 qv = q4[d4];
      v = make_float4(pv.x * qv.x, pv.y * qv.y, pv.z * qv.z, pv.w * qv.w);
    } else if (r < 2 * S_) {
      const float4* p4 = (const float4*)(p + (size_t)(b * S_ + (r - S_)) * D_);
      float4 pv = p4[d4];
      v = make_float4(pv.x * pv.x, pv.y * pv.y, pv.z * pv.z, pv.w * pv.w);
    } else {
      float4 qv = q4[d4];
      v = make_float4(qv.x * qv.x, qv.y * qv.y, qv.z * qv.z, qv.w * qv.w);
    }
  }
  ((float4*)A)[idx] = v;
}

__global__ __launch_bounds__(256)
void gemm_f32(const float* __restrict__ A, const float* __restrict__ W,
              float* __restrict__ G) {
  __shared__ float As[FBK][FBM];
  __shared__ float Ws[FBK][FBN];
  const int tid = threadIdx.x;
  const int m0 = blockIdx.y * FBM;
  const int n0 = blockIdx.x * FBN;
  const int tx = tid & 15;
  const int ty = tid >> 4;
  const int am = tid >> 2;
  const int ak0 = (tid & 3) << 2;
  const int wm = tid >> 1;
  const int wk0 = (tid & 1) << 3;
  const float* Ap = A + (size_t)(m0 + am) * D_ + ak0;
  const float* Wp = W + (size_t)(n0 + wm) * D_ + wk0;

  float acc[4][8];
#pragma unroll
  for (int i = 0; i < 4; ++i)
#pragma unroll
    for (int j = 0; j < 8; ++j) acc[i][j] = 0.f;

  for (int d0 = 0; d0 < D_; d0 += FBK) {
    float4 av = *(const float4*)(Ap + d0);
    float4 wv0 = *(const float4*)(Wp + d0);
    float4 wv1 = *(const float4*)(Wp + d0 + 4);
    __syncthreads();
    As[ak0 + 0][am] = av.x; As[ak0 + 1][am] = av.y;
    As[ak0 + 2][am] = av.z; As[ak0 + 3][am] = av.w;
    Ws[wk0 + 0][wm] = wv0.x * wv0.x; Ws[wk0 + 1][wm] = wv0.y * wv0.y;
    Ws[wk0 + 2][wm] = wv0.z * wv0.z; Ws[wk0 + 3][wm] = wv0.w * wv0.w;
    Ws[wk0 + 4][wm] = wv1.x * wv1.x; Ws[wk0 + 5][wm] = wv1.y * wv1.y;
    Ws[wk0 + 6][wm] = wv1.z * wv1.z; Ws[wk0 + 7][wm] = wv1.w * wv1.w;
    __syncthreads();
#pragma unroll
    for (int dk = 0; dk < FBK; ++dk) {
      float4 a = *(const float4*)&As[dk][ty << 2];
      float4 w0 = *(const float4*)&Ws[dk][tx << 2];
      float4 w1 = *(const float4*)&Ws[dk][64 + (tx << 2)];
      float ar[4] = {a.x, a.y, a.z, a.w};
      float wr[8] = {w0.x, w0.y, w0.z, w0.w, w1.x, w1.y, w1.z, w1.w};
#pragma unroll
      for (int i = 0; i < 4; ++i)
#pragma unroll
        for (int j = 0; j < 8; ++j) acc[i][j] += ar[i] * wr[j];
    }
  }
#pragma unroll
  for (int i = 0; i < 4; ++i) {
    float* row = G + (size_t)(m0 + (ty << 2) + i) * K_ + n0;
    *(float4*)(row + (tx << 2)) = make_float4(acc[i][0], acc[i][1], acc[i][2], acc[i][3]);
    *(float4*)(row + 64 + (tx << 2)) = make_float4(acc[i][4], acc[i][5], acc[i][6], acc[i][7]);
  }
}

__global__ __launch_bounds__(256)
void epilogue_f32(const float* __restrict__ G, float* __restrict__ out) {
  __shared__ float buf[256 * S_];
  const int tid = threadIdx.x;
  const int b = blockIdx.y;
  const int k0 = blockIdx.x * 256;
  const int k = k0 + tid;
  const float* Gb = G + (size_t)b * RPB * K_ + k;
  float nq = sqrtf(Gb[20 * K_]);
#pragma unroll
  for (int s = 0; s < S_; ++s) {
    float dot = Gb[s * K_];
    float np = sqrtf(Gb[(S_ + s) * K_]);
    buf[tid * S_ + s] = -dot / (np * nq * (float)D_);
  }
  __syncthreads();
  float* ob = out + ((size_t)b * K_ + k0) * S_;
  for (int i = tid; i < 256 * S_; i += 256) ob[i] = buf[i];
}

// ===========================================================================
extern "C" void kernel_launch(void* const* d_in, const int* in_sizes, int n_in,
                              void* d_out, int out_size, void* d_ws, size_t ws_size,
                              hipStream_t stream) {
  const float* p = (const float*)d_in[0];
  const float* q = (const float*)d_in[1];
  const float* W = (const float*)d_in[2];
  float* out = (float*)d_out;

  // MFMA path workspace layout (bytes):
  //   Whi 67108864 | Wlo 67108864 | Ahi 6291456 | Alo 6291456 | G 50331648
  const size_t WS_MFMA = 197132288;
  const size_t WS_F32 = (size_t)M_PAD_F32 * D_ * 4 + (size_t)M_PAD_F32 * K_ * 4;

  if (ws_size >= WS_MFMA) {
    uint8_t* w = (uint8_t*)d_ws;
    unsigned short* Whi = (unsigned short*)w;
    unsigned short* Wlo = (unsigned short*)(w + 67108864);
    unsigned short* Ahi = (unsigned short*)(w + 134217728);
    unsigned short* Alo = (unsigned short*)(w + 140509184);
    float* G = (float*)(w + 146800640);

    split_w<<<(K_ * (D_ / 4)) / 256, 256, 0, stream>>>(W, Whi, Wlo);
    build_a_split<<<(M_PAD_MF * (D_ / 4)) / 256, 256, 0, stream>>>(p, q, Ahi, Alo);
    dim3 ggrid(K_ / BN, M_PAD_MF / BM, KSPLIT);   // (64, 6, 2) = 768 blocks
    gemm_mfma<<<ggrid, 256, 0, stream>>>(Ahi, Alo, Whi, Wlo, G);
    epilogue2<<<dim3(K_ / 256, B_), 256, 0, stream>>>(G, out);
  } else {
    float* A = (float*)d_ws;
    float* G = A + (size_t)M_PAD_F32 * D_;
    build_A<<<(M_PAD_F32 * (D_ / 4)) / 256, 256, 0, stream>>>(p, q, A);
    dim3 ggrid(K_ / FBN, M_PAD_F32 / FBM);        // (64, 11)
    gemm_f32<<<ggrid, 256, 0, stream>>>(A, W, G);
    epilogue_f32<<<dim3(K_ / 256, B_), 256, 0, stream>>>(G, out);
  }
}

// Round 3
// 169.779 us; speedup vs baseline: 1.2831x; 1.2831x over previous
//
#include <hip/hip_runtime.h>
#include <stdint.h>

// Problem constants: B=32, S=10, D=4096, K=8192
#define B_ 32
#define S_ 10
#define D_ 4096
#define K_ 8192
#define RPB 21                 // rows per batch in A: 10 pq + 10 pp + 1 qq
#define M_REAL (B_ * RPB)      // 672

// ---------------- MFMA path geometry ----------------
#define BM 128
#define BN 128
#define BK 32
#define M_PAD_MF 768           // 6 tiles of 128
#define KSPLIT 2
#define KHALF (D_ / KSPLIT)    // 2048

typedef _Float16 f16x8 __attribute__((ext_vector_type(8)));
typedef float f32x4 __attribute__((ext_vector_type(4)));
typedef unsigned short us4 __attribute__((ext_vector_type(4)));

// f16 split helpers (RNE via cast; data has no nan/inf)
__device__ __forceinline__ unsigned short f2h(float x) {
  _Float16 h = (_Float16)x;
  union { _Float16 h; unsigned short u; } v; v.h = h;
  return v.u;
}
__device__ __forceinline__ float h2f(unsigned short u) {
  union { unsigned short u; _Float16 h; } v; v.u = u;
  return (float)v.h;
}

__device__ __forceinline__ void async16(const void* g, void* l) {
  __builtin_amdgcn_global_load_lds(
      (const __attribute__((address_space(1))) unsigned int*)g,
      (__attribute__((address_space(3))) unsigned int*)l, 16, 0, 0);
}

// ---------------------------------------------------------------------------
// Prepass 1: W2 = W*W (fp32), split into f16 hi/lo planes (2-term, ~22 bits).
// ---------------------------------------------------------------------------
__global__ __launch_bounds__(256)
void split_w(const float* __restrict__ W, unsigned short* __restrict__ Whi,
             unsigned short* __restrict__ Wlo) {
  size_t i4 = (size_t)blockIdx.x * 256 + threadIdx.x;   // over K_*D_/4 float4s
  float4 w = ((const float4*)W)[i4];
  float s[4] = {w.x * w.x, w.y * w.y, w.z * w.z, w.w * w.w};
  us4 hi, lo;
#pragma unroll
  for (int j = 0; j < 4; ++j) {
    unsigned short h = f2h(s[j]);
    ((unsigned short*)&hi)[j] = h;
    ((unsigned short*)&lo)[j] = f2h(s[j] - h2f(h));
  }
  ((us4*)Whi)[i4] = hi;
  ((us4*)Wlo)[i4] = lo;
}

// ---------------------------------------------------------------------------
// Prepass 2: build A rows (pq / pp / qq), quantize to a single f16 plane.
// ---------------------------------------------------------------------------
__global__ __launch_bounds__(256)
void build_a_f16(const float* __restrict__ p, const float* __restrict__ q,
                 unsigned short* __restrict__ Af) {
  size_t idx = (size_t)blockIdx.x * 256 + threadIdx.x;  // over M_PAD_MF * 1024 float4s
  int d4 = (int)(idx & 1023);
  int m = (int)(idx >> 10);
  float4 v = make_float4(0.f, 0.f, 0.f, 0.f);
  if (m < M_REAL) {
    int b = m / RPB;
    int r = m - b * RPB;
    const float4* q4 = (const float4*)(q + (size_t)(b * S_ + (S_ - 1)) * D_);
    if (r < S_) {
      const float4* p4 = (const float4*)(p + (size_t)(b * S_ + r) * D_);
      float4 pv = p4[d4]; float4 qv = q4[d4];
      v = make_float4(pv.x * qv.x, pv.y * qv.y, pv.z * qv.z, pv.w * qv.w);
    } else if (r < 2 * S_) {
      const float4* p4 = (const float4*)(p + (size_t)(b * S_ + (r - S_)) * D_);
      float4 pv = p4[d4];
      v = make_float4(pv.x * pv.x, pv.y * pv.y, pv.z * pv.z, pv.w * pv.w);
    } else {
      float4 qv = q4[d4];
      v = make_float4(qv.x * qv.x, qv.y * qv.y, qv.z * qv.z, qv.w * qv.w);
    }
  }
  us4 h;
  ((unsigned short*)&h)[0] = f2h(v.x);
  ((unsigned short*)&h)[1] = f2h(v.y);
  ((unsigned short*)&h)[2] = f2h(v.z);
  ((unsigned short*)&h)[3] = f2h(v.w);
  ((us4*)Af)[idx] = h;
}

// ---------------------------------------------------------------------------
// MFMA GEMM: G[ks][m][k] = sum_{d in half ks} Af[m][d] * (Whi+Wlo)[k][d]
// 2-term accumulate: Af*Whi + Af*Wlo  (f16 16x16x32 MFMA, f32 acc).
// 128x128x32 tile, 4 waves (2x2), wave tile 64x64 (4x4 frags of 16x16).
// global_load_lds (16B) into linear LDS with XOR-pre-swizzled global source.
// ---------------------------------------------------------------------------
__global__ __launch_bounds__(256)
void gemm_mfma(const unsigned short* __restrict__ Af,
               const unsigned short* __restrict__ Whi, const unsigned short* __restrict__ Wlo,
               float* __restrict__ G) {
  // 3 tiles of [128][32] f16 = 8KB each: 0=Af 1=Whi 2=Wlo
  __shared__ unsigned short lds[3 * 128 * 32];
  const int tid = threadIdx.x;
  const int lane = tid & 63;
  const int wid = tid >> 6;
  const int m0 = blockIdx.y * BM;
  const int n0 = blockIdx.x * BN;
  const int ks = blockIdx.z;
  const int d_base = ks * KHALF;

  // ---- staging setup: 6 global_load_lds issues per k-step ----
  const unsigned short* gp[6];
  uint32_t ldsoff[6];  // bytes, wave-uniform
  {
    const unsigned short* planes[3] = {Af, Whi, Wlo};
    const int rowg[3] = {m0, n0, n0};
#pragma unroll
    for (int t = 0; t < 3; ++t)
#pragma unroll
      for (int half = 0; half < 2; ++half) {
        int e = t * 2 + half;
        int row = half * 64 + wid * 16 + (lane >> 2);      // row within tile
        int k16l = (lane & 3) ^ ((row ^ (row >> 2)) & 3);  // pre-swizzled chunk
        gp[e] = planes[t] + (size_t)(rowg[t] + row) * D_ + d_base + k16l * 8;
        ldsoff[e] = (uint32_t)(t * 8192 + half * 4096 + wid * 1024);
      }
  }

  f32x4 acc[4][4];
#pragma unroll
  for (int i = 0; i < 4; ++i)
#pragma unroll
    for (int j = 0; j < 4; ++j) acc[i][j] = (f32x4){0.f, 0.f, 0.f, 0.f};

  const int wm = wid >> 1;        // wave row in 2x2 grid
  const int wn = wid & 1;
  const int frow = lane & 15;
  const int k16l = lane >> 4;
  int aoff[4], woff[4];           // element offsets within a tile
#pragma unroll
  for (int f = 0; f < 4; ++f) {
    int ra = wm * 64 + f * 16 + frow;
    aoff[f] = ra * 32 + ((k16l ^ ((ra ^ (ra >> 2)) & 3)) * 8);
    int rw = wn * 64 + f * 16 + frow;
    woff[f] = rw * 32 + ((k16l ^ ((rw ^ (rw >> 2)) & 3)) * 8);
  }
  const unsigned short* ldsA = lds;
  const unsigned short* ldsWhi = lds + 4096;
  const unsigned short* ldsWlo = lds + 8192;

  for (int d0 = 0; d0 < KHALF; d0 += BK) {
#pragma unroll
    for (int e = 0; e < 6; ++e)
      async16(gp[e] + d0, (char*)lds + ldsoff[e]);
    __syncthreads();              // drains vmcnt: staged data visible

    f16x8 aF[4];
#pragma unroll
    for (int f = 0; f < 4; ++f)
      aF[f] = *(const f16x8*)(ldsA + aoff[f]);
#pragma unroll
    for (int nf = 0; nf < 4; ++nf) {
      f16x8 wH = *(const f16x8*)(ldsWhi + woff[nf]);
      f16x8 wL = *(const f16x8*)(ldsWlo + woff[nf]);
#pragma unroll
      for (int mf = 0; mf < 4; ++mf) {
        acc[mf][nf] = __builtin_amdgcn_mfma_f32_16x16x32_f16(aF[mf], wH, acc[mf][nf], 0, 0, 0);
        acc[mf][nf] = __builtin_amdgcn_mfma_f32_16x16x32_f16(aF[mf], wL, acc[mf][nf], 0, 0, 0);
      }
    }
    __syncthreads();              // protect LDS before next iteration's DMA
  }

  // ---- C write: row=(lane>>4)*4+r, col=lane&15 (verified gfx950 C/D layout) ----
  float* Gp = G + (size_t)ks * M_PAD_MF * K_;
  const int crow = m0 + wm * 64;
  const int ccol = n0 + wn * 64;
#pragma unroll
  for (int mf = 0; mf < 4; ++mf)
#pragma unroll
    for (int nf = 0; nf < 4; ++nf)
#pragma unroll
      for (int r = 0; r < 4; ++r) {
        int row = crow + mf * 16 + (lane >> 4) * 4 + r;
        int col = ccol + nf * 16 + (lane & 15);
        Gp[(size_t)row * K_ + col] = acc[mf][nf][r];
      }
}

// ---------------------------------------------------------------------------
// Epilogue: sum K-split planes, normalize, transpose-write.
// out[b][k][s] = -dot / (sqrt(pp)*sqrt(qq)*D)
// ---------------------------------------------------------------------------
__global__ __launch_bounds__(256)
void epilogue2(const float* __restrict__ G, float* __restrict__ out) {
  __shared__ float buf[256 * S_];
  const int tid = threadIdx.x;
  const int b = blockIdx.y;
  const int k0 = blockIdx.x * 256;
  const int k = k0 + tid;
  const float* G0 = G + (size_t)b * RPB * K_ + k;
  const float* G1 = G0 + (size_t)M_PAD_MF * K_;
  float nq = sqrtf(G0[20 * K_] + G1[20 * K_]);
#pragma unroll
  for (int s = 0; s < S_; ++s) {
    float dot = G0[s * K_] + G1[s * K_];
    float pp = G0[(S_ + s) * K_] + G1[(S_ + s) * K_];
    buf[tid * S_ + s] = -dot / (sqrtf(pp) * nq * (float)D_);
  }
  __syncthreads();
  float* ob = out + ((size_t)b * K_ + k0) * S_;
  for (int i = tid; i < 256 * S_; i += 256) ob[i] = buf[i];
}

// ===========================================================================
// ============ fp32 fallback path (used if ws_size is too small) ============
// ===========================================================================
#define FBM 64
#define FBN 128
#define FBK 16
#define M_PAD_F32 704   // 11 tiles of 64

__global__ __launch_bounds__(256)
void build_A(const float* __restrict__ p, const float* __restrict__ q,
             float* __restrict__ A) {
  int idx = blockIdx.x * 256 + threadIdx.x;
  int d4 = idx & 1023;
  int m = idx >> 10;
  float4 v = make_float4(0.f, 0.f, 0.f, 0.f);
  if (m < M_REAL) {
    int b = m / RPB;
    int r = m - b * RPB;
    const float4* q4 = (const float4*)(q + (size_t)(b * S_ + (S_ - 1)) * D_);
    if (r < S_) {
      const float4* p4 = (const float4*)(p + (size_t)(b * S_ + r) * D_);
      float4 pv = p4[d4]; float4 qv = q4[d4];
      v = make_float4(pv.x * qv.x, pv.y * qv.y, pv.z * qv.z, pv.w * qv.w);
    } else if (r < 2 * S_) {
      const float4* p4 = (const float4*)(p + (size_t)(b * S_ + (r - S_)) * D_);
      float4 pv = p4[d4];
      v = make_float4(pv.x * pv.x, pv.y * pv.y, pv.z * pv.z, pv.w * pv.w);
    } else {
      float4 qv = q4[d4];
      v = make_float4(qv.x * qv.x, qv.y * qv.y, qv.z * qv.z, qv.w * qv.w);
    }
  }
  ((float4*)A)[idx] = v;
}

__global__ __launch_bounds__(256)
void gemm_f32(const float* __restrict__ A, const float* __restrict__ W,
              float* __restrict__ G) {
  __shared__ float As[FBK][FBM];
  __shared__ float Ws[FBK][FBN];
  const int tid = threadIdx.x;
  const int m0 = blockIdx.y * FBM;
  const int n0 = blockIdx.x * FBN;
  const int tx = tid & 15;
  const int ty = tid >> 4;
  const int am = tid >> 2;
  const int ak0 = (tid & 3) << 2;
  const int wm = tid >> 1;
  const int wk0 = (tid & 1) << 3;
  const float* Ap = A + (size_t)(m0 + am) * D_ + ak0;
  const float* Wp = W + (size_t)(n0 + wm) * D_ + wk0;

  float acc[4][8];
#pragma unroll
  for (int i = 0; i < 4; ++i)
#pragma unroll
    for (int j = 0; j < 8; ++j) acc[i][j] = 0.f;

  for (int d0 = 0; d0 < D_; d0 += FBK) {
    float4 av = *(const float4*)(Ap + d0);
    float4 wv0 = *(const float4*)(Wp + d0);
    float4 wv1 = *(const float4*)(Wp + d0 + 4);
    __syncthreads();
    As[ak0 + 0][am] = av.x; As[ak0 + 1][am] = av.y;
    As[ak0 + 2][am] = av.z; As[ak0 + 3][am] = av.w;
    Ws[wk0 + 0][wm] = wv0.x * wv0.x; Ws[wk0 + 1][wm] = wv0.y * wv0.y;
    Ws[wk0 + 2][wm] = wv0.z * wv0.z; Ws[wk0 + 3][wm] = wv0.w * wv0.w;
    Ws[wk0 + 4][wm] = wv1.x * wv1.x; Ws[wk0 + 5][wm] = wv1.y * wv1.y;
    Ws[wk0 + 6][wm] = wv1.z * wv1.z; Ws[wk0 + 7][wm] = wv1.w * wv1.w;
    __syncthreads();
#pragma unroll
    for (int dk = 0; dk < FBK; ++dk) {
      float4 a = *(const float4*)&As[dk][ty << 2];
      float4 w0 = *(const float4*)&Ws[dk][tx << 2];
      float4 w1 = *(const float4*)&Ws[dk][64 + (tx << 2)];
      float ar[4] = {a.x, a.y, a.z, a.w};
      float wr[8] = {w0.x, w0.y, w0.z, w0.w, w1.x, w1.y, w1.z, w1.w};
#pragma unroll
      for (int i = 0; i < 4; ++i)
#pragma unroll
        for (int j = 0; j < 8; ++j) acc[i][j] += ar[i] * wr[j];
    }
  }
#pragma unroll
  for (int i = 0; i < 4; ++i) {
    float* row = G + (size_t)(m0 + (ty << 2) + i) * K_ + n0;
    *(float4*)(row + (tx << 2)) = make_float4(acc[i][0], acc[i][1], acc[i][2], acc[i][3]);
    *(float4*)(row + 64 + (tx << 2)) = make_float4(acc[i][4], acc[i][5], acc[i][6], acc[i][7]);
  }
}

__global__ __launch_bounds__(256)
void epilogue_f32(const float* __restrict__ G, float* __restrict__ out) {
  __shared__ float buf[256 * S_];
  const int tid = threadIdx.x;
  const int b = blockIdx.y;
  const int k0 = blockIdx.x * 256;
  const int k = k0 + tid;
  const float* Gb = G + (size_t)b * RPB * K_ + k;
  float nq = sqrtf(Gb[20 * K_]);
#pragma unroll
  for (int s = 0; s < S_; ++s) {
    float dot = Gb[s * K_];
    float np = sqrtf(Gb[(S_ + s) * K_]);
    buf[tid * S_ + s] = -dot / (np * nq * (float)D_);
  }
  __syncthreads();
  float* ob = out + ((size_t)b * K_ + k0) * S_;
  for (int i = tid; i < 256 * S_; i += 256) ob[i] = buf[i];
}

// ===========================================================================
extern "C" void kernel_launch(void* const* d_in, const int* in_sizes, int n_in,
                              void* d_out, int out_size, void* d_ws, size_t ws_size,
                              hipStream_t stream) {
  const float* p = (const float*)d_in[0];
  const float* q = (const float*)d_in[1];
  const float* W = (const float*)d_in[2];
  float* out = (float*)d_out;

  // MFMA path workspace layout (bytes):
  //   Whi 67108864 | Wlo 67108864 | Af 6291456 | G 50331648
  const size_t WS_MFMA = 190840832;

  if (ws_size >= WS_MFMA) {
    uint8_t* w = (uint8_t*)d_ws;
    unsigned short* Whi = (unsigned short*)w;
    unsigned short* Wlo = (unsigned short*)(w + 67108864);
    unsigned short* Af  = (unsigned short*)(w + 134217728);
    float* G = (float*)(w + 140509184);

    split_w<<<(K_ * (D_ / 4)) / 256, 256, 0, stream>>>(W, Whi, Wlo);
    build_a_f16<<<(M_PAD_MF * (D_ / 4)) / 256, 256, 0, stream>>>(p, q, Af);
    dim3 ggrid(K_ / BN, M_PAD_MF / BM, KSPLIT);   // (64, 6, 2) = 768 blocks
    gemm_mfma<<<ggrid, 256, 0, stream>>>(Af, Whi, Wlo, G);
    epilogue2<<<dim3(K_ / 256, B_), 256, 0, stream>>>(G, out);
  } else {
    float* A = (float*)d_ws;
    float* G = A + (size_t)M_PAD_F32 * D_;
    build_A<<<(M_PAD_F32 * (D_ / 4)) / 256, 256, 0, stream>>>(p, q, A);
    dim3 ggrid(K_ / FBN, M_PAD_F32 / FBM);        // (64, 11)
    gemm_f32<<<ggrid, 256, 0, stream>>>(A, W, G);
    epilogue_f32<<<dim3(K_ / 256, B_), 256, 0, stream>>>(G, out);
  }
}

// Round 4
// 104.569 us; speedup vs baseline: 2.0832x; 1.6236x over previous
//
#include <hip/hip_runtime.h>
#include <stdint.h>

// Problem constants: B=32, S=10, D=4096, K=8192
#define B_ 32
#define S_ 10
#define D_ 4096
#define K_ 8192
#define RPB 21                 // rows per batch in A: 10 pq + 10 pp + 1 qq
#define M_REAL (B_ * RPB)      // 672

#define BM 128
#define BN 128
#define BK 32
#define M_PAD_MF 768           // 6 tiles of 128
#define KSPLIT 2
#define KHALF (D_ / KSPLIT)    // 2048

typedef _Float16 f16x8 __attribute__((ext_vector_type(8)));
typedef float f32x4 __attribute__((ext_vector_type(4)));
typedef unsigned short us4 __attribute__((ext_vector_type(4)));

__device__ __forceinline__ void async16(const void* g, void* l) {
  __builtin_amdgcn_global_load_lds(
      (const __attribute__((address_space(1))) unsigned int*)g,
      (__attribute__((address_space(3))) unsigned int*)l, 16, 0, 0);
}

// ---------------------------------------------------------------------------
// Prepass: build A rows (pq / pp / qq), quantize to a single f16 plane.
// ---------------------------------------------------------------------------
__global__ __launch_bounds__(256)
void build_a_f16(const float* __restrict__ p, const float* __restrict__ q,
                 unsigned short* __restrict__ Af) {
  size_t idx = (size_t)blockIdx.x * 256 + threadIdx.x;  // over M_PAD_MF * 1024 float4s
  int d4 = (int)(idx & 1023);
  int m = (int)(idx >> 10);
  float4 v = make_float4(0.f, 0.f, 0.f, 0.f);
  if (m < M_REAL) {
    int b = m / RPB;
    int r = m - b * RPB;
    const float4* q4 = (const float4*)(q + (size_t)(b * S_ + (S_ - 1)) * D_);
    if (r < S_) {
      const float4* p4 = (const float4*)(p + (size_t)(b * S_ + r) * D_);
      float4 pv = p4[d4]; float4 qv = q4[d4];
      v = make_float4(pv.x * qv.x, pv.y * qv.y, pv.z * qv.z, pv.w * qv.w);
    } else if (r < 2 * S_) {
      const float4* p4 = (const float4*)(p + (size_t)(b * S_ + (r - S_)) * D_);
      float4 pv = p4[d4];
      v = make_float4(pv.x * pv.x, pv.y * pv.y, pv.z * pv.z, pv.w * pv.w);
    } else {
      float4 qv = q4[d4];
      v = make_float4(qv.x * qv.x, qv.y * qv.y, qv.z * qv.z, qv.w * qv.w);
    }
  }
  us4 h;
  ((unsigned short*)&h)[0] = (unsigned short)__builtin_bit_cast(unsigned short, (_Float16)v.x);
  ((unsigned short*)&h)[1] = (unsigned short)__builtin_bit_cast(unsigned short, (_Float16)v.y);
  ((unsigned short*)&h)[2] = (unsigned short)__builtin_bit_cast(unsigned short, (_Float16)v.z);
  ((unsigned short*)&h)[3] = (unsigned short)__builtin_bit_cast(unsigned short, (_Float16)v.w);
  ((us4*)Af)[idx] = h;
}

// ---------------------------------------------------------------------------
// Fused MFMA GEMM: G[ks][m][k] = sum_{d in half ks} Af[m][d] * (W[k][d])^2
// Single f16 plane each side.  W is read as fp32 and squared+converted to
// f16 during reg-staging (global->reg->VALU->ds_write); A is staged via
// async global_load_lds with pre-swizzled source.
// 128x128x32 tile, 4 waves (2x2), wave tile 64x64 (4x4 frags of 16x16).
// LDS: A tile f16 [128][32] at byte 0 (8KB), W tile f16 [128][32] at 8192.
// Both tiles use the 16B-chunk XOR swizzle  phys_chunk = chunk ^ ((row^(row>>2))&3).
// ---------------------------------------------------------------------------
__global__ __launch_bounds__(256)
void gemm_mfma(const unsigned short* __restrict__ Af, const float* __restrict__ W,
               float* __restrict__ G) {
  __shared__ unsigned short lds[2 * 128 * 32];   // 16 KB
  const int tid = threadIdx.x;
  const int lane = tid & 63;
  const int wid = tid >> 6;
  const int m0 = blockIdx.y * BM;
  const int n0 = blockIdx.x * BN;
  const int ks = blockIdx.z;
  const int d_base = ks * KHALF;

  // ---- A staging: 2 async DMA issues per k-step, pre-swizzled global src ----
  const unsigned short* gpA[2];
  uint32_t ldsoffA[2];
#pragma unroll
  for (int half = 0; half < 2; ++half) {
    int row = half * 64 + wid * 16 + (lane >> 2);
    int k16l = (lane & 3) ^ ((row ^ (row >> 2)) & 3);
    gpA[half] = Af + (size_t)(m0 + row) * D_ + d_base + k16l * 8;
    ldsoffA[half] = (uint32_t)(half * 4096 + wid * 1024);   // bytes
  }

  // ---- W staging: thread t covers row=t>>1, floats [h*16, h*16+16) ----
  const int wrow = tid >> 1;
  const int wh = tid & 1;
  const float* gW = W + (size_t)(n0 + wrow) * D_ + d_base + wh * 16;
  const int wsz = (wrow ^ (wrow >> 2)) & 3;
  char* const ldsb = (char*)lds;
  char* const ldsWb = ldsb + 8192;
  const uint32_t wbyte0 = (uint32_t)(wrow * 64 + ((2 * wh) ^ wsz) * 16);
  const uint32_t wbyte1 = (uint32_t)(wrow * 64 + ((2 * wh + 1) ^ wsz) * 16);

  f32x4 acc[4][4];
#pragma unroll
  for (int i = 0; i < 4; ++i)
#pragma unroll
    for (int j = 0; j < 4; ++j) acc[i][j] = (f32x4){0.f, 0.f, 0.f, 0.f};

  const int wm = wid >> 1;        // wave row in 2x2 grid
  const int wn = wid & 1;
  const int frow = lane & 15;
  const int k16l = lane >> 4;
  int aoff[4], woff[4];           // byte offsets of fragments
#pragma unroll
  for (int f = 0; f < 4; ++f) {
    int ra = wm * 64 + f * 16 + frow;
    aoff[f] = ra * 64 + ((k16l ^ ((ra ^ (ra >> 2)) & 3)) * 16);
    int rw = wn * 64 + f * 16 + frow;
    woff[f] = rw * 64 + ((k16l ^ ((rw ^ (rw >> 2)) & 3)) * 16);
  }

  for (int d0 = 0; d0 < KHALF; d0 += BK) {
    // issue A DMA (async, drains at the barrier)
    async16(gpA[0] + d0, ldsb + ldsoffA[0]);
    async16(gpA[1] + d0, ldsb + ldsoffA[1]);
    // W: load fp32, square, convert, stage
    float4 w0 = *(const float4*)(gW + d0);
    float4 w1 = *(const float4*)(gW + d0 + 4);
    float4 w2 = *(const float4*)(gW + d0 + 8);
    float4 w3 = *(const float4*)(gW + d0 + 12);
    f16x8 o0, o1;
    o0[0] = (_Float16)(w0.x * w0.x); o0[1] = (_Float16)(w0.y * w0.y);
    o0[2] = (_Float16)(w0.z * w0.z); o0[3] = (_Float16)(w0.w * w0.w);
    o0[4] = (_Float16)(w1.x * w1.x); o0[5] = (_Float16)(w1.y * w1.y);
    o0[6] = (_Float16)(w1.z * w1.z); o0[7] = (_Float16)(w1.w * w1.w);
    o1[0] = (_Float16)(w2.x * w2.x); o1[1] = (_Float16)(w2.y * w2.y);
    o1[2] = (_Float16)(w2.z * w2.z); o1[3] = (_Float16)(w2.w * w2.w);
    o1[4] = (_Float16)(w3.x * w3.x); o1[5] = (_Float16)(w3.y * w3.y);
    o1[6] = (_Float16)(w3.z * w3.z); o1[7] = (_Float16)(w3.w * w3.w);
    *(f16x8*)(ldsWb + wbyte0) = o0;
    *(f16x8*)(ldsWb + wbyte1) = o1;
    __syncthreads();              // drains vmcnt (A DMA) + lgkm (ds_writes)

    f16x8 aF[4];
#pragma unroll
    for (int f = 0; f < 4; ++f)
      aF[f] = *(const f16x8*)(ldsb + aoff[f]);
#pragma unroll
    for (int nf = 0; nf < 4; ++nf) {
      f16x8 wF = *(const f16x8*)(ldsWb + woff[nf]);
#pragma unroll
      for (int mf = 0; mf < 4; ++mf)
        acc[mf][nf] = __builtin_amdgcn_mfma_f32_16x16x32_f16(aF[mf], wF, acc[mf][nf], 0, 0, 0);
    }
    __syncthreads();              // protect LDS before next iteration's staging
  }

  // ---- C write: row=(lane>>4)*4+r, col=lane&15 (verified gfx950 C/D layout) ----
  float* Gp = G + (size_t)ks * M_PAD_MF * K_;
  const int crow = m0 + wm * 64;
  const int ccol = n0 + wn * 64;
#pragma unroll
  for (int mf = 0; mf < 4; ++mf)
#pragma unroll
    for (int nf = 0; nf < 4; ++nf)
#pragma unroll
      for (int r = 0; r < 4; ++r) {
        int row = crow + mf * 16 + (lane >> 4) * 4 + r;
        int col = ccol + nf * 16 + (lane & 15);
        Gp[(size_t)row * K_ + col] = acc[mf][nf][r];
      }
}

// ---------------------------------------------------------------------------
// Epilogue: sum K-split planes, normalize, transpose-write.
// out[b][k][s] = -dot / (sqrt(pp)*sqrt(qq)*D)
// ---------------------------------------------------------------------------
__global__ __launch_bounds__(256)
void epilogue2(const float* __restrict__ G, float* __restrict__ out) {
  __shared__ float buf[256 * S_];
  const int tid = threadIdx.x;
  const int b = blockIdx.y;
  const int k0 = blockIdx.x * 256;
  const int k = k0 + tid;
  const float* G0 = G + (size_t)b * RPB * K_ + k;
  const float* G1 = G0 + (size_t)M_PAD_MF * K_;
  float nq = sqrtf(G0[20 * K_] + G1[20 * K_]);
#pragma unroll
  for (int s = 0; s < S_; ++s) {
    float dot = G0[s * K_] + G1[s * K_];
    float pp = G0[(S_ + s) * K_] + G1[(S_ + s) * K_];
    buf[tid * S_ + s] = -dot / (sqrtf(pp) * nq * (float)D_);
  }
  __syncthreads();
  float* ob = out + ((size_t)b * K_ + k0) * S_;
  for (int i = tid; i < 256 * S_; i += 256) ob[i] = buf[i];
}

// ===========================================================================
extern "C" void kernel_launch(void* const* d_in, const int* in_sizes, int n_in,
                              void* d_out, int out_size, void* d_ws, size_t ws_size,
                              hipStream_t stream) {
  const float* p = (const float*)d_in[0];
  const float* q = (const float*)d_in[1];
  const float* W = (const float*)d_in[2];
  float* out = (float*)d_out;

  // ws layout: Af [768][4096] f16 (6291456 B) | G [2][768][8192] f32 (50331648 B)
  uint8_t* w = (uint8_t*)d_ws;
  unsigned short* Af = (unsigned short*)w;
  float* G = (float*)(w + 6291456);

  build_a_f16<<<(M_PAD_MF * (D_ / 4)) / 256, 256, 0, stream>>>(p, q, Af);
  dim3 ggrid(K_ / BN, M_PAD_MF / BM, KSPLIT);   // (64, 6, 2) = 768 blocks
  gemm_mfma<<<ggrid, 256, 0, stream>>>(Af, W, G);
  epilogue2<<<dim3(K_ / 256, B_), 256, 0, stream>>>(G, out);
}

// Round 5
// 103.647 us; speedup vs baseline: 2.1018x; 1.0089x over previous
//
#include <hip/hip_runtime.h>
#include <stdint.h>

// Problem constants: B=32, S=10, D=4096, K=8192
#define B_ 32
#define S_ 10
#define D_ 4096
#define K_ 8192
#define RPB 21                 // rows per batch in A: 10 pq + 10 pp + 1 qq
#define M_REAL (B_ * RPB)      // 672

#define BM 128
#define BN 128
#define BK 32
#define M_PAD_MF 768           // 6 tiles of 128
#define KSPLIT 2
#define KHALF (D_ / KSPLIT)    // 2048
#define NSTEP (KHALF / BK)     // 64

typedef _Float16 f16x8 __attribute__((ext_vector_type(8)));
typedef float f32x4 __attribute__((ext_vector_type(4)));
typedef unsigned short us4 __attribute__((ext_vector_type(4)));

__device__ __forceinline__ void async16(const void* g, void* l) {
  __builtin_amdgcn_global_load_lds(
      (const __attribute__((address_space(1))) unsigned int*)g,
      (__attribute__((address_space(3))) unsigned int*)l, 16, 0, 0);
}

// ---------------------------------------------------------------------------
// Prepass: build A rows (pq / pp / qq), quantize to a single f16 plane.
// ---------------------------------------------------------------------------
__global__ __launch_bounds__(256)
void build_a_f16(const float* __restrict__ p, const float* __restrict__ q,
                 unsigned short* __restrict__ Af) {
  size_t idx = (size_t)blockIdx.x * 256 + threadIdx.x;  // over M_PAD_MF * 1024 float4s
  int d4 = (int)(idx & 1023);
  int m = (int)(idx >> 10);
  float4 v = make_float4(0.f, 0.f, 0.f, 0.f);
  if (m < M_REAL) {
    int b = m / RPB;
    int r = m - b * RPB;
    const float4* q4 = (const float4*)(q + (size_t)(b * S_ + (S_ - 1)) * D_);
    if (r < S_) {
      const float4* p4 = (const float4*)(p + (size_t)(b * S_ + r) * D_);
      float4 pv = p4[d4]; float4 qv = q4[d4];
      v = make_float4(pv.x * qv.x, pv.y * qv.y, pv.z * qv.z, pv.w * qv.w);
    } else if (r < 2 * S_) {
      const float4* p4 = (const float4*)(p + (size_t)(b * S_ + (r - S_)) * D_);
      float4 pv = p4[d4];
      v = make_float4(pv.x * pv.x, pv.y * pv.y, pv.z * pv.z, pv.w * pv.w);
    } else {
      float4 qv = q4[d4];
      v = make_float4(qv.x * qv.x, qv.y * qv.y, qv.z * qv.z, qv.w * qv.w);
    }
  }
  us4 h;
  ((unsigned short*)&h)[0] = (unsigned short)__builtin_bit_cast(unsigned short, (_Float16)v.x);
  ((unsigned short*)&h)[1] = (unsigned short)__builtin_bit_cast(unsigned short, (_Float16)v.y);
  ((unsigned short*)&h)[2] = (unsigned short)__builtin_bit_cast(unsigned short, (_Float16)v.z);
  ((unsigned short*)&h)[3] = (unsigned short)__builtin_bit_cast(unsigned short, (_Float16)v.w);
  ((us4*)Af)[idx] = h;
}

// ---------------------------------------------------------------------------
// Fused MFMA GEMM: G[ks][m][k] = sum_{d in half ks} Af[m][d] * (W[k][d])^2
// Software-pipelined (T14 issue-early/write-late):
//   - A: double-buffered LDS; DMA for step i+1 issued during compute(i).
//   - W: fp32 regs for step i+1 loaded during compute(i); squared+cvt+
//        ds_write at the top of staging(i+1).
// 128x128x32 tile, 4 waves (2x2), wave tile 64x64 (4x4 frags of 16x16).
// LDS: Abuf0 [0,8K), Abuf1 [8K,16K), W [16K,24K).  16B-chunk XOR swizzle
//   phys_chunk = chunk ^ ((row^(row>>2))&3)  on all tiles.
// ---------------------------------------------------------------------------
__global__ __launch_bounds__(256)
void gemm_mfma(const unsigned short* __restrict__ Af, const float* __restrict__ W,
               float* __restrict__ G) {
  __shared__ unsigned short lds[3 * 128 * 32];   // 24 KB
  const int tid = threadIdx.x;
  const int lane = tid & 63;
  const int wid = tid >> 6;
  const int m0 = blockIdx.y * BM;
  const int n0 = blockIdx.x * BN;
  const int ks = blockIdx.z;
  const int d_base = ks * KHALF;

  char* const ldsb = (char*)lds;          // A buffers at 0 and 8192
  char* const ldsWb = ldsb + 16384;       // W tile

  // ---- A staging: 2 async DMA issues per k-step, pre-swizzled global src ----
  const unsigned short* gpA[2];
  uint32_t ldsoffA[2];                    // within an A buffer (0..8K)
#pragma unroll
  for (int half = 0; half < 2; ++half) {
    int row = half * 64 + wid * 16 + (lane >> 2);
    int k16l = (lane & 3) ^ ((row ^ (row >> 2)) & 3);
    gpA[half] = Af + (size_t)(m0 + row) * D_ + d_base + k16l * 8;
    ldsoffA[half] = (uint32_t)(half * 4096 + wid * 1024);   // bytes
  }

  // ---- W staging: thread t covers row=t>>1, floats [h*16, h*16+16) ----
  const int wrow = tid >> 1;
  const int wh = tid & 1;
  const float* gW = W + (size_t)(n0 + wrow) * D_ + d_base + wh * 16;
  const int wsz = (wrow ^ (wrow >> 2)) & 3;
  const uint32_t wbyte0 = (uint32_t)(wrow * 64 + ((2 * wh) ^ wsz) * 16);
  const uint32_t wbyte1 = (uint32_t)(wrow * 64 + ((2 * wh + 1) ^ wsz) * 16);

  f32x4 acc[4][4];
#pragma unroll
  for (int i = 0; i < 4; ++i)
#pragma unroll
    for (int j = 0; j < 4; ++j) acc[i][j] = (f32x4){0.f, 0.f, 0.f, 0.f};

  const int wm = wid >> 1;        // wave row in 2x2 grid
  const int wn = wid & 1;
  const int frow = lane & 15;
  const int k16l = lane >> 4;
  int aoff[4], woff[4];           // byte offsets of fragments within a tile
#pragma unroll
  for (int f = 0; f < 4; ++f) {
    int ra = wm * 64 + f * 16 + frow;
    aoff[f] = ra * 64 + ((k16l ^ ((ra ^ (ra >> 2)) & 3)) * 16);
    int rw = wn * 64 + f * 16 + frow;
    woff[f] = rw * 64 + ((k16l ^ ((rw ^ (rw >> 2)) & 3)) * 16);
  }

  // ---- prologue: start step-0 A DMA (buf 0) and W register load ----
  async16(gpA[0], ldsb + ldsoffA[0]);
  async16(gpA[1], ldsb + ldsoffA[1]);
  float4 w0 = *(const float4*)(gW);
  float4 w1 = *(const float4*)(gW + 4);
  float4 w2 = *(const float4*)(gW + 8);
  float4 w3 = *(const float4*)(gW + 12);

  for (int i = 0; i < NSTEP; ++i) {
    // ---- staging phase i: square+cvt+write the prefetched W regs ----
    f16x8 o0, o1;
    o0[0] = (_Float16)(w0.x * w0.x); o0[1] = (_Float16)(w0.y * w0.y);
    o0[2] = (_Float16)(w0.z * w0.z); o0[3] = (_Float16)(w0.w * w0.w);
    o0[4] = (_Float16)(w1.x * w1.x); o0[5] = (_Float16)(w1.y * w1.y);
    o0[6] = (_Float16)(w1.z * w1.z); o0[7] = (_Float16)(w1.w * w1.w);
    o1[0] = (_Float16)(w2.x * w2.x); o1[1] = (_Float16)(w2.y * w2.y);
    o1[2] = (_Float16)(w2.z * w2.z); o1[3] = (_Float16)(w2.w * w2.w);
    o1[4] = (_Float16)(w3.x * w3.x); o1[5] = (_Float16)(w3.y * w3.y);
    o1[6] = (_Float16)(w3.z * w3.z); o1[7] = (_Float16)(w3.w * w3.w);
    *(f16x8*)(ldsWb + wbyte0) = o0;
    *(f16x8*)(ldsWb + wbyte1) = o1;
    __syncthreads();   // drains A-DMA(i) + W ds_writes: tiles visible

    // ---- compute phase i: prefetch step i+1, then MFMA on step i ----
    const int dn = (i + 1 < NSTEP) ? (i + 1) * BK : i * BK;  // clamped
    const uint32_t abN = (uint32_t)(((i + 1) & 1) * 8192);
    async16(gpA[0] + dn, ldsb + abN + ldsoffA[0]);
    async16(gpA[1] + dn, ldsb + abN + ldsoffA[1]);
    w0 = *(const float4*)(gW + dn);
    w1 = *(const float4*)(gW + dn + 4);
    w2 = *(const float4*)(gW + dn + 8);
    w3 = *(const float4*)(gW + dn + 12);

    const uint32_t ab = (uint32_t)((i & 1) * 8192);
    f16x8 aF[4];
#pragma unroll
    for (int f = 0; f < 4; ++f)
      aF[f] = *(const f16x8*)(ldsb + ab + aoff[f]);
#pragma unroll
    for (int nf = 0; nf < 4; ++nf) {
      f16x8 wF = *(const f16x8*)(ldsWb + woff[nf]);
#pragma unroll
      for (int mf = 0; mf < 4; ++mf)
        acc[mf][nf] = __builtin_amdgcn_mfma_f32_16x16x32_f16(aF[mf], wF, acc[mf][nf], 0, 0, 0);
    }
    __syncthreads();   // all waves done reading W tile + A buf(i) before rewrite
  }

  // ---- C write: row=(lane>>4)*4+r, col=lane&15 (verified gfx950 C/D layout) ----
  float* Gp = G + (size_t)ks * M_PAD_MF * K_;
  const int crow = m0 + wm * 64;
  const int ccol = n0 + wn * 64;
#pragma unroll
  for (int mf = 0; mf < 4; ++mf)
#pragma unroll
    for (int nf = 0; nf < 4; ++nf)
#pragma unroll
      for (int r = 0; r < 4; ++r) {
        int row = crow + mf * 16 + (lane >> 4) * 4 + r;
        int col = ccol + nf * 16 + (lane & 15);
        Gp[(size_t)row * K_ + col] = acc[mf][nf][r];
      }
}

// ---------------------------------------------------------------------------
// Epilogue: sum K-split planes, normalize, transpose-write.
// out[b][k][s] = -dot / (sqrt(pp)*sqrt(qq)*D)
// ---------------------------------------------------------------------------
__global__ __launch_bounds__(256)
void epilogue2(const float* __restrict__ G, float* __restrict__ out) {
  __shared__ float buf[256 * S_];
  const int tid = threadIdx.x;
  const int b = blockIdx.y;
  const int k0 = blockIdx.x * 256;
  const int k = k0 + tid;
  const float* G0 = G + (size_t)b * RPB * K_ + k;
  const float* G1 = G0 + (size_t)M_PAD_MF * K_;
  float nq = sqrtf(G0[20 * K_] + G1[20 * K_]);
#pragma unroll
  for (int s = 0; s < S_; ++s) {
    float dot = G0[s * K_] + G1[s * K_];
    float pp = G0[(S_ + s) * K_] + G1[(S_ + s) * K_];
    buf[tid * S_ + s] = -dot / (sqrtf(pp) * nq * (float)D_);
  }
  __syncthreads();
  float* ob = out + ((size_t)b * K_ + k0) * S_;
  for (int i = tid; i < 256 * S_; i += 256) ob[i] = buf[i];
}

// ===========================================================================
extern "C" void kernel_launch(void* const* d_in, const int* in_sizes, int n_in,
                              void* d_out, int out_size, void* d_ws, size_t ws_size,
                              hipStream_t stream) {
  const float* p = (const float*)d_in[0];
  const float* q = (const float*)d_in[1];
  const float* W = (const float*)d_in[2];
  float* out = (float*)d_out;

  // ws layout: Af [768][4096] f16 (6291456 B) | G [2][768][8192] f32 (50331648 B)
  uint8_t* w = (uint8_t*)d_ws;
  unsigned short* Af = (unsigned short*)w;
  float* G = (float*)(w + 6291456);

  build_a_f16<<<(M_PAD_MF * (D_ / 4)) / 256, 256, 0, stream>>>(p, q, Af);
  dim3 ggrid(K_ / BN, M_PAD_MF / BM, KSPLIT);   // (64, 6, 2) = 768 blocks
  gemm_mfma<<<ggrid, 256, 0, stream>>>(Af, W, G);
  epilogue2<<<dim3(K_ / 256, B_), 256, 0, stream>>>(G, out);
}